// Round 11
// baseline (277.727 us; speedup 1.0000x reference)
//
#include <hip/hip_runtime.h>

// EfConv forward, CSR-based, fp16 payloads, atomic-free permute.
// R11 experiment: 16-PLANE SPLIT HISTOGRAM — deg16[h][node], h=blockIdx&15.
// Tests whether the 68us atomic wall is per-cache-line serialization (splitting
// helps ~8-16x) or central atomic-pipe rate (split is neutral). rank packs
// (plane<<26)|local; merge kernel turns planes into per-plane exclusive bases.
//   M0 memset:    deg16[:]=0  (16*N ints)
//   K1 fused, 3 block ranges:
//       [0,nbH):        local=deg16[bid&15][dst[e]]++; rank[e]=(h<<26)|local
//       [nbH,nbH+nbC):  efh[e]=fp16(ef[e][:])
//       [nbH+nbC,...):  t = fp16(node_feat @ W^T)
//   K2 merge+partials: per-node: exclusive prefix over 16 planes (in place),
//       deg[n]=total; block-reduce -> partials
//   K3 addback:  offsets (redundant LDS scan of partials + local scan)
//   K4 permute:  pos=offsets[d]+deg16[h][d]+local; srcs[pos]=src; efs[pos]=efh[e]
//   K5 aggregate: per node (one wave, lanes=o), 16-deep gather chains, fp32 acc,
//       scalar-path srcs/efs, NT stores for coalesced write-once out.

#define FEATS 64
#define EDGE_DIM 8
#define NPLANE 16
#define PLANE_SHIFT 26
#define LOCAL_MASK ((1u << PLANE_SHIFT) - 1u)

typedef _Float16 half8 __attribute__((ext_vector_type(8)));
typedef float f32x4 __attribute__((ext_vector_type(4)));

// ---- K1: fused hist(8/thread, 16 planes) + ef->fp16 convert + transform ----
__global__ void __launch_bounds__(256) fused_kernel(
    const int* __restrict__ dst, int* __restrict__ deg16,
    unsigned* __restrict__ rank, int n_edges, int nbH, int nbC,
    const float* __restrict__ ef, half8* __restrict__ efh,
    const float* __restrict__ nf, const float* __restrict__ W,
    _Float16* __restrict__ t, int n_nodes)
{
    const int tid = threadIdx.x;
    const unsigned bid = blockIdx.x;

    if (bid < (unsigned)nbH) {
        // ---- histogram into plane h: local = deg16[h][dst]++ ; 8 chains ----
        const unsigned h = bid & (NPLANE - 1);
        int* __restrict__ degp = deg16 + (long)h * n_nodes;
        const unsigned htag = h << PLANE_SHIFT;
        long i8 = ((long)bid * 256 + tid) * 8;
        if (i8 + 7 < n_edges) {
            int4 d0 = *(const int4*)(dst + i8);
            int4 d1 = *(const int4*)(dst + i8 + 4);
            uint4 r0, r1;
            r0.x = htag | (unsigned)atomicAdd(&degp[d0.x], 1);
            r0.y = htag | (unsigned)atomicAdd(&degp[d0.y], 1);
            r0.z = htag | (unsigned)atomicAdd(&degp[d0.z], 1);
            r0.w = htag | (unsigned)atomicAdd(&degp[d0.w], 1);
            r1.x = htag | (unsigned)atomicAdd(&degp[d1.x], 1);
            r1.y = htag | (unsigned)atomicAdd(&degp[d1.y], 1);
            r1.z = htag | (unsigned)atomicAdd(&degp[d1.z], 1);
            r1.w = htag | (unsigned)atomicAdd(&degp[d1.w], 1);
            *(uint4*)(rank + i8)     = r0;           // coalesced
            *(uint4*)(rank + i8 + 4) = r1;
        } else {
            for (long e = i8; e < n_edges; ++e)
                rank[e] = htag | (unsigned)atomicAdd(&degp[dst[e]], 1);
        }
        return;
    }

    if (bid < (unsigned)(nbH + nbC)) {
        // ---- convert: efh[e] = fp16(ef[e][:]), fully coalesced ----
        int e = (bid - nbH) * 256 + tid;
        if (e < n_edges) {
            const f32x4* q = (const f32x4*)(ef + (long)e * EDGE_DIM);
            f32x4 a = q[0], c = q[1];
            half8 hh;
            hh[0] = (_Float16)a.x; hh[1] = (_Float16)a.y;
            hh[2] = (_Float16)a.z; hh[3] = (_Float16)a.w;
            hh[4] = (_Float16)c.x; hh[5] = (_Float16)c.y;
            hh[6] = (_Float16)c.z; hh[7] = (_Float16)c.w;
            efh[e] = hh;
        }
        return;
    }

    // ---- transform: t[n][o] = fp16(sum_i nf[n][i]*W[o][i]) ----
    __shared__ float sWt[FEATS * 65];
    __shared__ float srow[4][FEATS];
    const int bt = bid - nbH - nbC;

    #pragma unroll
    for (int base = 0; base < FEATS * FEATS; base += 256) {
        int idx = base + tid;
        int o = idx >> 6;
        int i = idx & 63;
        sWt[i * 65 + o] = W[idx];
    }

    const int r = tid >> 6;
    const int o = tid & 63;
    const int node = bt * 4 + r;
    if (node < n_nodes) srow[r][o] = nf[(long)node * FEATS + o];
    __syncthreads();

    if (node >= n_nodes) return;
    float sum = 0.f;
    #pragma unroll
    for (int i = 0; i < FEATS; i++)
        sum += srow[r][i] * sWt[i * 65 + o];
    t[(long)node * FEATS + o] = (_Float16)sum;   // single rounding, fp32 accumulate
}

// ---- K2: per-node plane prefix (in place) + deg + per-block partial sums ----
__global__ void __launch_bounds__(256) merge_partials_kernel(
    int* __restrict__ deg16, int* __restrict__ deg,
    int* __restrict__ partials, int n)
{
    __shared__ int s[256];
    const int tid = threadIdx.x;
    int i = blockIdx.x * 256 + tid;
    int tot = 0;
    if (i < n) {
        int run = 0;
        #pragma unroll
        for (int x = 0; x < NPLANE; x++) {
            long idx = (long)x * n + i;          // each plane read/write coalesced
            int c = deg16[idx];
            deg16[idx] = run;                    // exclusive base of plane x
            run += c;
        }
        deg[i] = run;
        tot = run;
    }
    s[tid] = tot;
    __syncthreads();
    for (int off = 128; off > 0; off >>= 1) {
        if (tid < off) s[tid] += s[tid + off];
        __syncthreads();
    }
    if (tid == 0) partials[blockIdx.x] = s[0];
}

// ---- K3: merged partials-scan (redundant per block) + local scan + addback ----
__global__ void __launch_bounds__(256) scan_addback_kernel(
    const int* __restrict__ deg, const int* __restrict__ partials,
    int* __restrict__ offsets, int nb, int n, int n_edges)
{
    __shared__ int sp[256];
    __shared__ int s[256];
    const int tid = threadIdx.x;

    sp[tid] = (tid < nb) ? partials[tid] : 0;
    for (int off = 1; off < 256; off <<= 1) {
        __syncthreads();
        int x = (tid >= off) ? sp[tid - off] : 0;
        __syncthreads();
        sp[tid] += x;
    }

    int i = blockIdx.x * 256 + tid;
    int v = (i < n) ? deg[i] : 0;
    s[tid] = v;
    for (int off = 1; off < 256; off <<= 1) {
        __syncthreads();
        int x = (tid >= off) ? s[tid - off] : 0;
        __syncthreads();
        s[tid] += x;
    }
    __syncthreads();

    if (i < n) {
        int pbase = (blockIdx.x == 0) ? 0 : sp[blockIdx.x - 1];
        offsets[i] = pbase + s[tid] - v;
    }
    if (blockIdx.x == 0 && tid == 0) offsets[n] = n_edges;
}

// ---- K4: atomic-free permute; pos = offsets[d] + planebase[h][d] + local ----
__global__ void __launch_bounds__(256) permute_ef_kernel(
    const int* __restrict__ src, const int* __restrict__ dst,
    const unsigned* __restrict__ rank, const int* __restrict__ offsets,
    const int* __restrict__ deg16, const half8* __restrict__ efh,
    int* __restrict__ srcs, half8* __restrict__ efs, int n_edges, int n_nodes)
{
    int i4 = (blockIdx.x * 256 + threadIdx.x) * 4;
    if (i4 + 3 < n_edges) {
        int4 s = *(const int4*)(src + i4);
        int4 d = *(const int4*)(dst + i4);
        uint4 r = *(const uint4*)(rank + i4);
        // independent gathers in flight: offsets (200KB) + plane bases (3.2MB), L2-hot
        int p0 = offsets[d.x] + deg16[(long)(r.x >> PLANE_SHIFT) * n_nodes + d.x]
               + (int)(r.x & LOCAL_MASK);
        int p1 = offsets[d.y] + deg16[(long)(r.y >> PLANE_SHIFT) * n_nodes + d.y]
               + (int)(r.y & LOCAL_MASK);
        int p2 = offsets[d.z] + deg16[(long)(r.z >> PLANE_SHIFT) * n_nodes + d.z]
               + (int)(r.z & LOCAL_MASK);
        int p3 = offsets[d.w] + deg16[(long)(r.w >> PLANE_SHIFT) * n_nodes + d.w]
               + (int)(r.w & LOCAL_MASK);
        half8 h0 = efh[i4], h1 = efh[i4 + 1], h2 = efh[i4 + 2], h3 = efh[i4 + 3];
        efs[p0] = h0;                            // plain stores: L2 write-combines
        efs[p1] = h1;
        efs[p2] = h2;
        efs[p3] = h3;
        srcs[p0] = s.x; srcs[p1] = s.y; srcs[p2] = s.z; srcs[p3] = s.w;
    } else {
        for (int e = i4; e < n_edges; ++e) {
            unsigned rr = rank[e];
            int dd = dst[e];
            int p = offsets[dd] + deg16[(long)(rr >> PLANE_SHIFT) * n_nodes + dd]
                  + (int)(rr & LOCAL_MASK);
            srcs[p] = src[e];
            efs[p] = efh[e];
        }
    }
}

// ---- K5: per-node aggregation, 16-deep chains, scalar fp16 ef ----
#define CHUNK 16

__global__ void __launch_bounds__(256) aggregate_seq_kernel(
    const _Float16* __restrict__ t, const half8* __restrict__ efs,
    const int* __restrict__ srcs, const int* __restrict__ offsets,
    const float* __restrict__ b, float* __restrict__ out, int n_nodes)
{
    const int node = __builtin_amdgcn_readfirstlane(
        (int)((blockIdx.x * 256 + threadIdx.x) >> 6));
    const int o = threadIdx.x & 63;
    if (node >= n_nodes) return;

    const int beg = offsets[node];
    const int end = offsets[node + 1];
    float acc[EDGE_DIM];
    #pragma unroll
    for (int k = 0; k < EDGE_DIM; k++) acc[k] = 0.f;

    if (end > beg) {
        const int last = end - 1;      // >= beg >= 0, so clamped idx always valid
        for (int j = beg; j < end; j += CHUNK) {
            int sidx[CHUNK];
            #pragma unroll
            for (int u = 0; u < CHUNK; u++) {
                int jj = j + u;
                sidx[u] = srcs[jj <= last ? jj : last];   // uniform clamp (scalar)
            }
            float tv[CHUNK];
            #pragma unroll
            for (int u = 0; u < CHUNK; u++)               // CHUNK gathers in flight
                tv[u] = (float)t[(long)sidx[u] * FEATS + o];
            #pragma unroll
            for (int u = 0; u < CHUNK; u++) {
                int jj = j + u;
                int ej = jj <= last ? jj : last;
                float tvm = (jj <= last) ? tv[u] : 0.f;   // mask tail
                half8 row = efs[ej];                      // uniform 16B (scalar path)
                #pragma unroll
                for (int k = 0; k < EDGE_DIM; k++)
                    acc[k] += (float)row[k] * tvm;
            }
        }
    }

    const float bo = b[o];
    float* op = out + (long)node * (EDGE_DIM * FEATS) + o;
    // out IS coalesced/full-line: NT is correct here (write-once stream)
    #pragma unroll
    for (int k = 0; k < EDGE_DIM; k++)
        __builtin_nontemporal_store(acc[k] + bo, op + k * FEATS);
}

extern "C" void kernel_launch(void* const* d_in, const int* in_sizes, int n_in,
                              void* d_out, int out_size, void* d_ws, size_t ws_size,
                              hipStream_t stream) {
    const float* node_feat = (const float*)d_in[0];
    const float* edge_feat = (const float*)d_in[1];
    const float* W         = (const float*)d_in[2];
    const float* b         = (const float*)d_in[3];
    const int*   src       = (const int*)d_in[4];
    const int*   dst       = (const int*)d_in[5];
    float* out = (float*)d_out;

    const int n_nodes = in_sizes[0] / FEATS;
    const int n_edges = in_sizes[4];
    const int nb_nodes = (n_nodes + 255) / 256;        // <= 256 required by scan
    const int nbH = (n_edges + 2047) / 2048;           // hist blocks, 8 edges/thread
    const int nbC = (n_edges + 255) / 256;             // convert blocks, 1 edge/thread
    const int nbT = (n_nodes + 3) / 4;                 // transform blocks
    const int nbP = (n_edges + 1023) / 1024;           // permute blocks, 4 edges/thread

    // workspace layout (4B units)
    int* w = (int*)d_ws;
    _Float16* t   = (_Float16*)w;                      // N*64 halves = N*32 ints
    int* deg16    = w + (long)n_nodes * (FEATS / 2);   // 16*N
    int* deg      = deg16 + (long)NPLANE * n_nodes;    // N
    int* offsets  = deg + n_nodes;                     // N+1
    int* partials = offsets + n_nodes + 1;             // 256
    unsigned* rank = (unsigned*)(partials + 256);      // E
    int* srcs     = (int*)(rank + n_edges);            // E
    uintptr_t ha  = ((uintptr_t)(srcs + n_edges) + 15) & ~(uintptr_t)15;
    half8* efh    = (half8*)ha;                        // E * 16B (orig order)
    half8* efs    = efh + n_edges;                     // E * 16B (dst-sorted)

    hipMemsetAsync(deg16, 0, (size_t)NPLANE * n_nodes * 4, stream);
    fused_kernel<<<nbH + nbC + nbT, 256, 0, stream>>>(
        dst, deg16, rank, n_edges, nbH, nbC, edge_feat, efh,
        node_feat, W, t, n_nodes);
    merge_partials_kernel<<<nb_nodes, 256, 0, stream>>>(deg16, deg, partials, n_nodes);
    scan_addback_kernel<<<nb_nodes, 256, 0, stream>>>(deg, partials, offsets,
                                                      nb_nodes, n_nodes, n_edges);
    permute_ef_kernel<<<nbP, 256, 0, stream>>>(src, dst, rank, offsets, deg16, efh,
                                               srcs, efs, n_edges, n_nodes);

    const long total_ag = (long)n_nodes * 64;
    aggregate_seq_kernel<<<(int)((total_ag + 255) / 256), 256, 0, stream>>>(
        t, efs, srcs, offsets, b, out, n_nodes);
}